// Round 7
// baseline (1393.385 us; speedup 1.0000x reference)
//
#include <hip/hip_runtime.h>
#include <hip/hip_bf16.h>
#include <stdint.h>

typedef _Float16 f16;
typedef _Float16 f16x2 __attribute__((ext_vector_type(2)));
typedef _Float16 f16x4 __attribute__((ext_vector_type(4)));
typedef _Float16 f16x8 __attribute__((ext_vector_type(8)));
typedef float f32x4 __attribute__((ext_vector_type(4)));
typedef int   i32x4 __attribute__((ext_vector_type(4)));

#define T_STEPS 512
#define BATCH   128
#define DD      512
#define LOG2E   1.44269504088896f

// workspace layout (bytes)
#define XP_OFF  0                            // f16 Xproj' [512][128][512] = 67,108,864
#define WF_OFF  (67108864)                   // f16 W_in  [512][512]      =    524,288
#define WHQ_OFF (67108864 + 524288)          // i8  W_h frag-packed       =    262,144
#define SC_OFF  (67108864 + 524288 + 262144) // f32 row scales2 [512]     =      2,048
#define CNT_OFF (SC_OFF + 2048)              // i32 panel counters [512]  =      2,048

__device__ __forceinline__ f16x2 pk(float a, float b) {
    return __builtin_bit_cast(f16x2, __builtin_amdgcn_cvt_pkrtz(a, b));
}

__device__ __forceinline__ float fast_exp2(float x) {
#if __has_builtin(__builtin_amdgcn_exp2f)
    return __builtin_amdgcn_exp2f(x);
#else
    return exp2f(x);
#endif
}

__device__ __forceinline__ float fast_rcp(float x) {
#if __has_builtin(__builtin_amdgcn_rcpf)
    return __builtin_amdgcn_rcpf(x);
#else
    return 1.0f / x;
#endif
}

__device__ __forceinline__ uint32_t pack_u8(float s, int pos, uint32_t old) {
#if __has_builtin(__builtin_amdgcn_cvt_pk_u8_f32)
    return __builtin_amdgcn_cvt_pk_u8_f32(s, pos, old);
#else
    return old | (((uint32_t)(int)s & 0xFF) << (8 * pos));
#endif
}

#define GLDS(g, l) __builtin_amdgcn_global_load_lds(                               \
        (const __attribute__((address_space(1))) void*)(g),                        \
        (__attribute__((address_space(3))) void*)(l), 16, 0, 0)

// ------------------------------------------------ prep: Wf (f16 W_in) + zero panel flags
__global__ __launch_bounds__(256) void prep_kernel(
        const float* __restrict__ Win, f16* __restrict__ Wf, int* __restrict__ cnt) {
    int idx = blockIdx.x * 256 + threadIdx.x;
    if (idx < 262144) Wf[idx] = (f16)Win[idx];
    if (idx < 512) cnt[idx] = 0;     // re-zeroed every launch (graph replays!)
}

// ------------------------------------------- quantize W_h to i8, frag-packed, per-row scale
__global__ __launch_bounds__(64) void quant_kernel(
        const float* __restrict__ Wh, char* __restrict__ Whq, float* __restrict__ scales) {
    const int o = blockIdx.x, t = threadIdx.x;
    const float* row = Wh + (size_t)o * 512;
    float v[8];
    float m = 0.f;
#pragma unroll
    for (int j = 0; j < 8; j++) { v[j] = row[t * 8 + j]; m = fmaxf(m, fabsf(v[j])); }
#pragma unroll
    for (int off = 32; off > 0; off >>= 1) m = fmaxf(m, __shfl_xor(m, off));
    if (t == 0) scales[o] = -LOG2E * m * (1.0f / (127.0f * 127.0f));
    const float inv = 127.0f / m;
    const int rt = o >> 4, rl = o & 15;
    const int k0 = t * 8;
    const int ks = k0 >> 6, qq = (k0 >> 4) & 3, j0 = k0 & 15;
    const int l = qq * 16 + rl;
    char* dst = Whq + ((size_t)((rt * 8 + ks) * 64 + l)) * 16 + j0;
#pragma unroll
    for (int j = 0; j < 8; j++) dst[j] = (char)rintf(v[j] * inv);
}

// ============================ FUSED producer-consumer kernel =============================
// rnn needs only Xp panel t at step t, not the whole gemm. Blocks 0..7: EXACT R1 rnn
// (449us, verified R5/R6) + per-wave flag polls. Blocks 8..1031: gemm producer, one
// 128x256 half-panel each (R5 math, 16 waves), dispatched in t-order; panel pair 8 blocks
// apart -> same XCD -> A panel L2-shared. Release: threadfence (agent: L2 writeback) +
// barrier + device-scope atomicAdd(cnt[panel]); ready when cnt[panel]==2. Consumer polls
// 64 flags at once (lane-vector acquire loads + ballot prefix) with a watermark ->
// steady-state ~1 poll per 64 steps. Producer never waits; rnn occupies <=8 CUs ->
// no deadlock regardless of dispatch order. LDS union 64KB.
__global__ __launch_bounds__(1024, 4) void fused_kernel(
        const float* __restrict__ X, const f16* __restrict__ Wf,
        const float* __restrict__ bias, f16* __restrict__ Xp,
        const char* __restrict__ Whq, const float* __restrict__ scales,
        int* __restrict__ cnt, float* __restrict__ out) {
    __shared__ __align__(16) char smem[65536];
    const int tid = threadIdx.x;
    const int l = tid & 63, w = tid >> 6;          // 16 waves

    if (blockIdx.x >= 8) {
        // --------------------------- gemm producer role ---------------------------
        float (*As)[128 * 32] = (float (*)[128 * 32])smem;           // 2 x 16 KB
        f16   (*Bs)[256 * 32] = (f16 (*)[256 * 32])(smem + 32768);   // 2 x 16 KB
        const int b0 = (int)blockIdx.x - 8;
        const int panel = ((b0 >> 4) << 3) | (b0 & 7);   // pairs (b, b+8) share a panel
        const int half  = (b0 >> 3) & 1;
        const int m_blk = panel * 128;
        const int n_blk = half * 256;
        const int q = l >> 4, rl = l & 15;
        const int wm = w >> 2, wn = w & 3;           // wm 0..3 (32 rows), wn 0..3 (64 cols)

        // A staging: wave w stages rows [8w,8w+8); row = 8w+(l>>3), src chunk (l&7)^(l>>3)
        const float* aSrc = X + (size_t)(m_blk + w * 8 + (l >> 3)) * 512
                              + (((l & 7) ^ (l >> 3)) << 2);
        // B staging: wave w stages rows [16w,16w+16); row = 16w+(l>>2), chunk (l&3)^((l>>3)&3)
        const f16* bSrc = Wf + (size_t)(n_blk + w * 16 + (l >> 2)) * 512
                             + (((l & 3) ^ ((l >> 3) & 3)) << 3);

        f32x4 acc[2][4] = {};
        const int swA0 = (((2 * q)     ^ (rl & 7)) << 2);   // float units
        const int swA1 = (((2 * q + 1) ^ (rl & 7)) << 2);
        const int swB  = ((q ^ ((rl >> 1) & 3)) << 3);      // f16 units

        GLDS(aSrc, &As[0][(w * 8) * 32]);
        GLDS(bSrc, &Bs[0][(w * 16) * 32]);

        for (int t = 0; t < 16; ++t) {
            const int cur = t & 1;
            __syncthreads();   // tile cur staged (drains own vmcnt); cur^1 free
            if (t < 15) {
                const int kf = (t + 1) * 32;
                GLDS(aSrc + kf, &As[cur ^ 1][(w * 8) * 32]);
                GLDS(bSrc + kf, &Bs[cur ^ 1][(w * 16) * 32]);
            }
            f16x8 af4[2], bf4[4];
#pragma unroll
            for (int i = 0; i < 2; i++) {
                const int row = wm * 32 + i * 16 + rl;
                const float4 h0 = *(const float4*)&As[cur][row * 32 + swA0];
                const float4 h1 = *(const float4*)&As[cur][row * 32 + swA1];
                f16x2 p0 = pk(h0.x, h0.y), p1 = pk(h0.z, h0.w);
                f16x2 p2 = pk(h1.x, h1.y), p3 = pk(h1.z, h1.w);
                f16x8 tv;
                tv[0] = p0[0]; tv[1] = p0[1]; tv[2] = p1[0]; tv[3] = p1[1];
                tv[4] = p2[0]; tv[5] = p2[1]; tv[6] = p3[0]; tv[7] = p3[1];
                af4[i] = tv;
            }
#pragma unroll
            for (int j = 0; j < 4; j++) {
                const int row = wn * 64 + j * 16 + rl;
                bf4[j] = *(const f16x8*)&Bs[cur][row * 32 + swB];
            }
            // swapped operands: D row = n (q*4+r), D col = m (rl)
#pragma unroll
            for (int i = 0; i < 2; i++)
#pragma unroll
                for (int j = 0; j < 4; j++)
                    acc[i][j] = __builtin_amdgcn_mfma_f32_16x16x32_f16(bf4[j], af4[i], acc[i][j], 0, 0, 0);
        }
        // epilogue: n = n_blk+wn*64+j*16+q*4+r, m = m_blk+wm*32+i*16+rl
#pragma unroll
        for (int j = 0; j < 4; j++) {
            const float4 b4 = *(const float4*)&bias[n_blk + wn * 64 + j * 16 + q * 4];
            const float bb[4] = {b4.x, b4.y, b4.z, b4.w};
#pragma unroll
            for (int i = 0; i < 2; i++) {
                const int m = m_blk + wm * 32 + i * 16 + rl;
                f16x4 v;
#pragma unroll
                for (int r = 0; r < 4; r++)
                    v[r] = (f16)(-LOG2E * (acc[i][j][r] + bb[r]));   // RTE, same as R5
                *(f16x4*)(Xp + (size_t)m * 512 + n_blk + wn * 64 + j * 16 + q * 4) = v;
            }
        }
        // release: writes visible device-wide, then bump panel counter
        __threadfence();
        __syncthreads();
        if (tid == 0)
            __hip_atomic_fetch_add(cnt + panel, 1, __ATOMIC_RELEASE, __HIP_MEMORY_SCOPE_AGENT);
        return;
    }

    // ------------------------------ rnn consumer role ------------------------------
    // EXACT R1 structure (449us) + flag gating before each Xp prefetch.
    uint32_t* hT = (uint32_t*)smem;     // [2][2048], 16 KB
    const int wg = blockIdx.x;          // 0..7
    const int bl = l & 15;
    const int q = l >> 4;
    const int b = wg * 16 + bl;

    i32x4 af[2][8];
    {
        const i32x4* wp = (const i32x4*)Whq;
#pragma unroll
        for (int mt = 0; mt < 2; mt++)
#pragma unroll
            for (int ks = 0; ks < 8; ks++)
                af[mt][ks] = wp[((w * 2 + mt) * 8 + ks) * 64 + l];
    }
    float sc[2][4];
#pragma unroll
    for (int mt = 0; mt < 2; mt++)
#pragma unroll
        for (int r = 0; r < 4; r++)
            sc[mt][r] = scales[w * 32 + mt * 16 + q * 4 + r];

    for (int i = tid; i < 2048; i += 1024) hT[i] = 0u;
    __syncthreads();

    // per-wave watermark poll: panels [0, wmk) known ready (cnt==2).
    int wmk = 0;
#define ENSURE(n) do {                                                                     \
        while (wmk <= (n)) {                                                               \
            const int idx_ = wmk + l;                                                      \
            int v_ = (idx_ < 512)                                                          \
                ? __hip_atomic_load(cnt + idx_, __ATOMIC_ACQUIRE, __HIP_MEMORY_SCOPE_AGENT)\
                : 2;                                                                       \
            unsigned long long m_ = __ballot(v_ >= 2);                                     \
            unsigned long long inv_ = ~m_;                                                 \
            int pre_ = inv_ ? (int)__builtin_ctzll(inv_) : 64;                             \
            if (pre_ == 0) __builtin_amdgcn_s_sleep(32);                                   \
            wmk += pre_;                                                                   \
        }                                                                                  \
    } while (0)

    const f16* xpb = Xp + (size_t)b * 512 + w * 32 + q * 4;
    ENSURE(0);
    f16x4 xn0 = *(const f16x4*)(xpb);
    f16x4 xn1 = *(const f16x4*)(xpb + 16);

    const float K127 = 1.0f / 127.0f;
    for (int t = 0; t < T_STEPS; t++) {
        f16x4 xc0 = xn0, xc1 = xn1;
        if (t < T_STEPS - 1) ENSURE(t + 1);
        const size_t tn = (size_t)(t < T_STEPS - 1 ? t + 1 : t) * (BATCH * 512);
        xn0 = *(const f16x4*)(xpb + tn);
        xn1 = *(const f16x4*)(xpb + tn + 16);

        const int rb = t & 1;
        i32x4 acc[2] = {};
        const uint32_t* hrow = hT + rb * 2048 + l * 4;
#pragma unroll
        for (int ks = 0; ks < 8; ks++) {
            i32x4 bfr = *(const i32x4*)(hrow + ks * 256);
            acc[0] = __builtin_amdgcn_mfma_i32_16x16x64_i8(af[0][ks], bfr, acc[0], 0, 0, 0);
            acc[1] = __builtin_amdgcn_mfma_i32_16x16x64_i8(af[1][ks], bfr, acc[1], 0, 0, 0);
        }
#pragma unroll
        for (int mt = 0; mt < 2; mt++) {
            uint32_t pkq = 0;
#pragma unroll
            for (int r = 0; r < 4; r++) {
                float tt = fmaf((float)acc[mt][r], sc[mt][r], (float)(mt == 0 ? xc0[r] : xc1[r]));
                float e  = fast_exp2(tt);                // e^{-v}
                float eq = fmaf(e, K127, K127);          // (1+e^{-v})/127
                float sg = fast_rcp(eq) + 0.5f;          // 127*sigmoid + 0.5
                pkq = pack_u8(sg, r, pkq);
            }
            hT[(1 - rb) * 2048 + (w * 2 + mt) * 64 + bl * 4 + q] = pkq;
        }
        __syncthreads();
    }
#undef ENSURE
#pragma unroll
    for (int mt = 0; mt < 2; mt++) {
        uint32_t pkq = hT[(T_STEPS & 1) * 2048 + (w * 2 + mt) * 64 + bl * 4 + q];
        float4 o;
        o.x = (float)((pkq      ) & 0xFF) * K127;
        o.y = (float)((pkq >>  8) & 0xFF) * K127;
        o.z = (float)((pkq >> 16) & 0xFF) * K127;
        o.w = (float)((pkq >> 24) & 0xFF) * K127;
        *(float4*)(out + (size_t)b * 512 + w * 32 + mt * 16 + q * 4) = o;
    }
}

extern "C" void kernel_launch(void* const* d_in, const int* in_sizes, int n_in,
                              void* d_out, int out_size, void* d_ws, size_t ws_size,
                              hipStream_t stream) {
    const float* X   = (const float*)d_in[0];
    const float* Win = (const float*)d_in[1];
    const float* Wh  = (const float*)d_in[2];
    const float* bh  = (const float*)d_in[3];
    float* out = (float*)d_out;
    char* ws = (char*)d_ws;
    f16* Xp      = (f16*)(ws + XP_OFF);
    f16* Wf      = (f16*)(ws + WF_OFF);
    char* Whq    = (char*)(ws + WHQ_OFF);
    float* Sc    = (float*)(ws + SC_OFF);
    int* Cnt     = (int*)(ws + CNT_OFF);

    prep_kernel<<<1024, 256, 0, stream>>>(Win, Wf, Cnt);
    quant_kernel<<<512, 64, 0, stream>>>(Wh, Whq, Sc);
    fused_kernel<<<1032, 1024, 0, stream>>>(X, Wf, bh, Xp, Whq, Sc, Cnt, out);
}

// Round 8
// 1297.901 us; speedup vs baseline: 1.0736x; 1.0736x over previous
//
#include <hip/hip_runtime.h>
#include <hip/hip_bf16.h>
#include <stdint.h>

typedef _Float16 f16;
typedef _Float16 f16x2 __attribute__((ext_vector_type(2)));
typedef _Float16 f16x4 __attribute__((ext_vector_type(4)));
typedef _Float16 f16x8 __attribute__((ext_vector_type(8)));
typedef float f32x4 __attribute__((ext_vector_type(4)));
typedef int   i32x4 __attribute__((ext_vector_type(4)));

#define T_STEPS 512
#define BATCH   128
#define DD      512
#define LOG2E   1.44269504088896f
#define NHP     1024     // half-panels (512 panels x 2)

// workspace layout (bytes)
#define XP_OFF  0                            // f16 Xproj' [512][128][512] = 67,108,864
#define WF_OFF  (67108864)                   // f16 W_in  [512][512]      =    524,288
#define WHQ_OFF (67108864 + 524288)          // i8  W_h frag-packed       =    262,144
#define SC_OFF  (67108864 + 524288 + 262144) // f32 row scales2 [512]     =      2,048
#define AUX_OFF (SC_OFF + 2048)              // i32 aux[544]: [0..511] cnt, [512] queue
                                             //               [528..535] rnn CU ids

__device__ __forceinline__ f16x2 pk(float a, float b) {
    return __builtin_bit_cast(f16x2, __builtin_amdgcn_cvt_pkrtz(a, b));
}

__device__ __forceinline__ float fast_exp2(float x) {
#if __has_builtin(__builtin_amdgcn_exp2f)
    return __builtin_amdgcn_exp2f(x);
#else
    return exp2f(x);
#endif
}

__device__ __forceinline__ float fast_rcp(float x) {
#if __has_builtin(__builtin_amdgcn_rcpf)
    return __builtin_amdgcn_rcpf(x);
#else
    return 1.0f / x;
#endif
}

__device__ __forceinline__ uint32_t pack_u8(float s, int pos, uint32_t old) {
#if __has_builtin(__builtin_amdgcn_cvt_pk_u8_f32)
    return __builtin_amdgcn_cvt_pk_u8_f32(s, pos, old);
#else
    return old | (((uint32_t)(int)s & 0xFF) << (8 * pos));
#endif
}

// physical CU id: HW_ID (id=4, full 32b: CU[11:8] SH[12] SE[15:13]) + XCC_ID (id=20).
// numeric hwreg encodings (id | (size-1)<<11) avoid named-hwreg asm parsing.
__device__ __forceinline__ int cu_gid() {
    int hwid = __builtin_amdgcn_s_getreg(63492);   // 4  | 31<<11
    int xcc  = __builtin_amdgcn_s_getreg(63508);   // 20 | 31<<11
    return ((xcc & 0xFF) << 16) | (hwid & 0xFF00);
}

#define GLDS(g, l) __builtin_amdgcn_global_load_lds(                               \
        (const __attribute__((address_space(1))) void*)(g),                        \
        (__attribute__((address_space(3))) void*)(l), 16, 0, 0)

// ------------------------------------------------ prep: Wf (f16 W_in) + zero aux state
__global__ __launch_bounds__(256) void prep_kernel(
        const float* __restrict__ Win, f16* __restrict__ Wf, int* __restrict__ aux) {
    int idx = blockIdx.x * 256 + threadIdx.x;
    if (idx < 262144) Wf[idx] = (f16)Win[idx];
    if (idx < 544) aux[idx] = (idx >= 528) ? -1 : 0;   // re-init every launch (graph replay)
}

// ------------------------------------------- quantize W_h to i8, frag-packed, per-row scale
__global__ __launch_bounds__(64) void quant_kernel(
        const float* __restrict__ Wh, char* __restrict__ Whq, float* __restrict__ scales) {
    const int o = blockIdx.x, t = threadIdx.x;
    const float* row = Wh + (size_t)o * 512;
    float v[8];
    float m = 0.f;
#pragma unroll
    for (int j = 0; j < 8; j++) { v[j] = row[t * 8 + j]; m = fmaxf(m, fabsf(v[j])); }
#pragma unroll
    for (int off = 32; off > 0; off >>= 1) m = fmaxf(m, __shfl_xor(m, off));
    if (t == 0) scales[o] = -LOG2E * m * (1.0f / (127.0f * 127.0f));
    const float inv = 127.0f / m;
    const int rt = o >> 4, rl = o & 15;
    const int k0 = t * 8;
    const int ks = k0 >> 6, qq = (k0 >> 4) & 3, j0 = k0 & 15;
    const int l = qq * 16 + rl;
    char* dst = Whq + ((size_t)((rt * 8 + ks) * 64 + l)) * 16 + j0;
#pragma unroll
    for (int j = 0; j < 8; j++) dst[j] = (char)rintf(v[j] * inv);
}

// ============================ FUSED producer-consumer kernel =============================
// R8 vs R7: grid 256 (8 rnn + 248 PERSISTENT producers pulling half-panels from a
// device-scope atomic queue). R7's regression was co-residency: 1032 blocks @64KB LDS
// -> 2/CU -> every rnn CU shared with a producer -> rnn critical path 2.8x. Now:
// 256 blocks -> likely 1/CU; and politeness insurance: rnn blocks publish their physical
// CU id, a producer co-resident with an rnn block takes NO queue items (sleeps until
// queue drained, then exits). <=8 producers can be polite -> >=240 active -> no
// starvation; producers never wait on consumers -> no deadlock.
__global__ __launch_bounds__(1024, 4) void fused_kernel(
        const float* __restrict__ X, const f16* __restrict__ Wf,
        const float* __restrict__ bias, f16* __restrict__ Xp,
        const char* __restrict__ Whq, const float* __restrict__ scales,
        int* __restrict__ aux, float* __restrict__ out) {
    __shared__ __align__(16) char smem[65536];
    int* cnt   = aux;
    int* queue = aux + 512;
    int* rnnCU = aux + 528;
    const int tid = threadIdx.x;
    const int l = tid & 63, w = tid >> 6;          // 16 waves

    if (blockIdx.x >= 8) {
        // --------------------------- persistent gemm producer ---------------------------
        float (*As)[128 * 32] = (float (*)[128 * 32])smem;           // 2 x 16 KB
        f16   (*Bs)[256 * 32] = (f16 (*)[256 * 32])(smem + 32768);   // 2 x 16 KB
        volatile int* hslot = (volatile int*)smem;                   // scratch broadcast
        const int q = l >> 4, rl = l & 15;
        const int wm = w >> 2, wn = w & 3;
        const int swA0 = (((2 * q)     ^ (rl & 7)) << 2);   // float units
        const int swA1 = (((2 * q + 1) ^ (rl & 7)) << 2);
        const int swB  = ((q ^ ((rl >> 1) & 3)) << 3);      // f16 units

        for (;;) {
            __syncthreads();                     // (a) prior smem reads complete
            if (tid == 0) {
                const int me = cu_gid();
                int shared = 0;
#pragma unroll
                for (int i = 0; i < 8; i++)
                    shared |= (__hip_atomic_load(rnnCU + i, __ATOMIC_ACQUIRE,
                                                 __HIP_MEMORY_SCOPE_AGENT) == me);
                int h;
                if (shared) {   // polite: take no work; exit once queue drained
                    h = (__hip_atomic_load(queue, __ATOMIC_RELAXED,
                                           __HIP_MEMORY_SCOPE_AGENT) >= NHP) ? NHP : -1;
                } else {
                    h = __hip_atomic_fetch_add(queue, 1, __ATOMIC_RELAXED,
                                               __HIP_MEMORY_SCOPE_AGENT);
                }
                *hslot = h;
            }
            __syncthreads();                     // (b) h visible
            const int h = *hslot;
            __syncthreads();                     // (c) everyone read; smem reusable
            if (h >= NHP) return;
            if (h < 0) { __builtin_amdgcn_s_sleep(64); continue; }

            const int panel = h >> 1, half = h & 1;
            const int m_blk = panel * 128;
            const int n_blk = half * 256;
            // A: wave w stages rows [8w,8w+8); row = 8w+(l>>3), src chunk (l&7)^(l>>3)
            const float* aSrc = X + (size_t)(m_blk + w * 8 + (l >> 3)) * 512
                                  + (((l & 7) ^ (l >> 3)) << 2);
            // B: wave w stages rows [16w,16w+16); row = 16w+(l>>2), chunk (l&3)^((l>>3)&3)
            const f16* bSrc = Wf + (size_t)(n_blk + w * 16 + (l >> 2)) * 512
                                 + (((l & 3) ^ ((l >> 3) & 3)) << 3);

            f32x4 acc[2][4] = {};
            GLDS(aSrc, &As[0][(w * 8) * 32]);
            GLDS(bSrc, &Bs[0][(w * 16) * 32]);

            for (int t = 0; t < 16; ++t) {
                const int cur = t & 1;
                __syncthreads();   // tile cur staged (drains own vmcnt); cur^1 free
                if (t < 15) {
                    const int kf = (t + 1) * 32;
                    GLDS(aSrc + kf, &As[cur ^ 1][(w * 8) * 32]);
                    GLDS(bSrc + kf, &Bs[cur ^ 1][(w * 16) * 32]);
                }
                f16x8 af4[2], bf4[4];
#pragma unroll
                for (int i = 0; i < 2; i++) {
                    const int row = wm * 32 + i * 16 + rl;
                    const float4 h0 = *(const float4*)&As[cur][row * 32 + swA0];
                    const float4 h1 = *(const float4*)&As[cur][row * 32 + swA1];
                    f16x2 p0 = pk(h0.x, h0.y), p1 = pk(h0.z, h0.w);
                    f16x2 p2 = pk(h1.x, h1.y), p3 = pk(h1.z, h1.w);
                    f16x8 tv;
                    tv[0] = p0[0]; tv[1] = p0[1]; tv[2] = p1[0]; tv[3] = p1[1];
                    tv[4] = p2[0]; tv[5] = p2[1]; tv[6] = p3[0]; tv[7] = p3[1];
                    af4[i] = tv;
                }
#pragma unroll
                for (int j = 0; j < 4; j++) {
                    const int row = wn * 64 + j * 16 + rl;
                    bf4[j] = *(const f16x8*)&Bs[cur][row * 32 + swB];
                }
                // swapped operands: D row = n (q*4+r), D col = m (rl)
#pragma unroll
                for (int i = 0; i < 2; i++)
#pragma unroll
                    for (int j = 0; j < 4; j++)
                        acc[i][j] = __builtin_amdgcn_mfma_f32_16x16x32_f16(bf4[j], af4[i], acc[i][j], 0, 0, 0);
            }
            // epilogue: n = n_blk+wn*64+j*16+q*4+r, m = m_blk+wm*32+i*16+rl
#pragma unroll
            for (int j = 0; j < 4; j++) {
                const float4 b4 = *(const float4*)&bias[n_blk + wn * 64 + j * 16 + q * 4];
                const float bb[4] = {b4.x, b4.y, b4.z, b4.w};
#pragma unroll
                for (int i = 0; i < 2; i++) {
                    const int m = m_blk + wm * 32 + i * 16 + rl;
                    f16x4 v;
#pragma unroll
                    for (int r = 0; r < 4; r++)
                        v[r] = (f16)(-LOG2E * (acc[i][j][r] + bb[r]));   // RTE, same as R5
                    *(f16x4*)(Xp + (size_t)m * 512 + n_blk + wn * 64 + j * 16 + q * 4) = v;
                }
            }
            // release: writes visible device-wide, then bump panel counter
            __threadfence();
            __syncthreads();
            if (tid == 0)
                __hip_atomic_fetch_add(cnt + panel, 1, __ATOMIC_RELEASE,
                                       __HIP_MEMORY_SCOPE_AGENT);
        }
    }

    // ------------------------------ rnn consumer role ------------------------------
    // EXACT R1 structure (449us, verified R5/R6) + CU-id publish + flag gating.
    uint32_t* hT = (uint32_t*)smem;     // [2][2048], 16 KB
    const int wg = blockIdx.x;          // 0..7
    const int bl = l & 15;
    const int q = l >> 4;
    const int b = wg * 16 + bl;

    if (tid == 0)
        __hip_atomic_store(rnnCU + wg, cu_gid(), __ATOMIC_RELEASE,
                           __HIP_MEMORY_SCOPE_AGENT);

    i32x4 af[2][8];
    {
        const i32x4* wp = (const i32x4*)Whq;
#pragma unroll
        for (int mt = 0; mt < 2; mt++)
#pragma unroll
            for (int ks = 0; ks < 8; ks++)
                af[mt][ks] = wp[((w * 2 + mt) * 8 + ks) * 64 + l];
    }
    float sc[2][4];
#pragma unroll
    for (int mt = 0; mt < 2; mt++)
#pragma unroll
        for (int r = 0; r < 4; r++)
            sc[mt][r] = scales[w * 32 + mt * 16 + q * 4 + r];

    for (int i = tid; i < 2048; i += 1024) hT[i] = 0u;
    __syncthreads();

    // per-wave watermark poll: panels [0, wmk) known ready (cnt==2).
    int wmk = 0;
#define ENSURE(n) do {                                                                     \
        while (wmk <= (n)) {                                                               \
            const int idx_ = wmk + l;                                                      \
            int v_ = (idx_ < 512)                                                          \
                ? __hip_atomic_load(cnt + idx_, __ATOMIC_ACQUIRE, __HIP_MEMORY_SCOPE_AGENT)\
                : 2;                                                                       \
            unsigned long long m_ = __ballot(v_ >= 2);                                     \
            unsigned long long inv_ = ~m_;                                                 \
            int pre_ = inv_ ? (int)__builtin_ctzll(inv_) : 64;                             \
            if (pre_ == 0) __builtin_amdgcn_s_sleep(32);                                   \
            wmk += pre_;                                                                   \
        }                                                                                  \
    } while (0)

    const f16* xpb = Xp + (size_t)b * 512 + w * 32 + q * 4;
    ENSURE(0);
    f16x4 xn0 = *(const f16x4*)(xpb);
    f16x4 xn1 = *(const f16x4*)(xpb + 16);

    const float K127 = 1.0f / 127.0f;
    for (int t = 0; t < T_STEPS; t++) {
        f16x4 xc0 = xn0, xc1 = xn1;
        if (t < T_STEPS - 1) ENSURE(t + 1);
        const size_t tn = (size_t)(t < T_STEPS - 1 ? t + 1 : t) * (BATCH * 512);
        xn0 = *(const f16x4*)(xpb + tn);
        xn1 = *(const f16x4*)(xpb + tn + 16);

        const int rb = t & 1;
        i32x4 acc[2] = {};
        const uint32_t* hrow = hT + rb * 2048 + l * 4;
#pragma unroll
        for (int ks = 0; ks < 8; ks++) {
            i32x4 bfr = *(const i32x4*)(hrow + ks * 256);
            acc[0] = __builtin_amdgcn_mfma_i32_16x16x64_i8(af[0][ks], bfr, acc[0], 0, 0, 0);
            acc[1] = __builtin_amdgcn_mfma_i32_16x16x64_i8(af[1][ks], bfr, acc[1], 0, 0, 0);
        }
#pragma unroll
        for (int mt = 0; mt < 2; mt++) {
            uint32_t pkq = 0;
#pragma unroll
            for (int r = 0; r < 4; r++) {
                float tt = fmaf((float)acc[mt][r], sc[mt][r], (float)(mt == 0 ? xc0[r] : xc1[r]));
                float e  = fast_exp2(tt);                // e^{-v}
                float eq = fmaf(e, K127, K127);          // (1+e^{-v})/127
                float sg = fast_rcp(eq) + 0.5f;          // 127*sigmoid + 0.5
                pkq = pack_u8(sg, r, pkq);
            }
            hT[(1 - rb) * 2048 + (w * 2 + mt) * 64 + bl * 4 + q] = pkq;
        }
        __syncthreads();
    }
#undef ENSURE
#pragma unroll
    for (int mt = 0; mt < 2; mt++) {
        uint32_t pkq = hT[(T_STEPS & 1) * 2048 + (w * 2 + mt) * 64 + bl * 4 + q];
        float4 o;
        o.x = (float)((pkq      ) & 0xFF) * K127;
        o.y = (float)((pkq >>  8) & 0xFF) * K127;
        o.z = (float)((pkq >> 16) & 0xFF) * K127;
        o.w = (float)((pkq >> 24) & 0xFF) * K127;
        *(float4*)(out + (size_t)b * 512 + w * 32 + mt * 16 + q * 4) = o;
    }
}

extern "C" void kernel_launch(void* const* d_in, const int* in_sizes, int n_in,
                              void* d_out, int out_size, void* d_ws, size_t ws_size,
                              hipStream_t stream) {
    const float* X   = (const float*)d_in[0];
    const float* Win = (const float*)d_in[1];
    const float* Wh  = (const float*)d_in[2];
    const float* bh  = (const float*)d_in[3];
    float* out = (float*)d_out;
    char* ws = (char*)d_ws;
    f16* Xp      = (f16*)(ws + XP_OFF);
    f16* Wf      = (f16*)(ws + WF_OFF);
    char* Whq    = (char*)(ws + WHQ_OFF);
    float* Sc    = (float*)(ws + SC_OFF);
    int* Aux     = (int*)(ws + AUX_OFF);

    prep_kernel<<<1024, 256, 0, stream>>>(Win, Wf, Aux);
    quant_kernel<<<512, 64, 0, stream>>>(Wh, Whq, Sc);
    fused_kernel<<<256, 1024, 0, stream>>>(X, Wf, bh, Xp, Whq, Sc, Aux, out);
}

// Round 9
// 805.169 us; speedup vs baseline: 1.7306x; 1.6120x over previous
//
#include <hip/hip_runtime.h>
#include <hip/hip_bf16.h>
#include <stdint.h>

typedef _Float16 f16;
typedef _Float16 f16x2 __attribute__((ext_vector_type(2)));
typedef _Float16 f16x4 __attribute__((ext_vector_type(4)));
typedef _Float16 f16x8 __attribute__((ext_vector_type(8)));
typedef float f32x4 __attribute__((ext_vector_type(4)));
typedef int   i32x4 __attribute__((ext_vector_type(4)));

#define T_STEPS 512
#define BATCH   128
#define DD      512
#define LOG2E   1.44269504088896f

// workspace layout (bytes)
#define XP_OFF  0                          // f16 Xproj' [512][128][512] = 67,108,864
#define WF_OFF  (67108864)                 // f16 W_in  [512][512]      =    524,288
#define WHQ_OFF (67108864 + 524288)        // i8  W_h frag-packed       =    262,144
#define SC_OFF  (67108864 + 524288 + 262144) // f32 row scales2 [512]   =      2,048

__device__ __forceinline__ f16x2 pk(float a, float b) {
    return __builtin_bit_cast(f16x2, __builtin_amdgcn_cvt_pkrtz(a, b));
}

__device__ __forceinline__ float fast_exp2(float x) {
#if __has_builtin(__builtin_amdgcn_exp2f)
    return __builtin_amdgcn_exp2f(x);
#else
    return exp2f(x);
#endif
}

__device__ __forceinline__ float fast_rcp(float x) {
#if __has_builtin(__builtin_amdgcn_rcpf)
    return __builtin_amdgcn_rcpf(x);
#else
    return 1.0f / x;
#endif
}

__device__ __forceinline__ uint32_t pack_u8(float s, int pos, uint32_t old) {
#if __has_builtin(__builtin_amdgcn_cvt_pk_u8_f32)
    return __builtin_amdgcn_cvt_pk_u8_f32(s, pos, old);
#else
    return old | (((uint32_t)(int)s & 0xFF) << (8 * pos));
#endif
}

// ---------------------------------------------------------------- prep: Wf (f16 W_in)
__global__ __launch_bounds__(256) void prep_kernel(
        const float* __restrict__ Win, f16* __restrict__ Wf) {
    int idx = blockIdx.x * 256 + threadIdx.x;
    if (idx < 262144) Wf[idx] = (f16)Win[idx];
}

// ------------------------------------------- quantize W_h to i8, frag-packed, per-row scale
// one wave per output row o. A-frag packing: byte index
//   ((rt*8+ks)*64 + l)*16 + j  ->  W_h[out][k],  rt = o>>4
//   out = rt*16+(l&15), k = ks*64+(l>>4)*16+j
// scales2[o] = -log2e * m/(127*127): epilogue computes t = acc*sc2 + xp2 = -log2e*v.
__global__ __launch_bounds__(64) void quant_kernel(
        const float* __restrict__ Wh, char* __restrict__ Whq, float* __restrict__ scales) {
    const int o = blockIdx.x, t = threadIdx.x;
    const float* row = Wh + (size_t)o * 512;
    float v[8];
    float m = 0.f;
#pragma unroll
    for (int j = 0; j < 8; j++) { v[j] = row[t * 8 + j]; m = fmaxf(m, fabsf(v[j])); }
#pragma unroll
    for (int off = 32; off > 0; off >>= 1) m = fmaxf(m, __shfl_xor(m, off));
    if (t == 0) scales[o] = -LOG2E * m * (1.0f / (127.0f * 127.0f));
    const float inv = 127.0f / m;
    const int rt = o >> 4, rl = o & 15;
    const int k0 = t * 8;
    const int ks = k0 >> 6, qq = (k0 >> 4) & 3, j0 = k0 & 15;
    const int l = qq * 16 + rl;
    char* dst = Whq + ((size_t)((rt * 8 + ks) * 64 + l)) * 16 + j0;
#pragma unroll
    for (int j = 0; j < 8; j++) dst[j] = (char)rintf(v[j] * inv);
}

// ------------------------------------------------- Xproj' = -log2e*(X @ Win^T + b_h), f16
// EXACT best-measured gemm (671.75us total, Round-1 bench): direct-from-global MFMA,
// register double-buffered prefetch of next k0 tile. Barrier-free (no LDS): 4 waves/block,
// each 64x64 out, acc[4][4]. Seven structural rewrites (LDS 2-buf, 3-buf counted-vmcnt,
// f16-A, 4 tile shapes, 2 fusions) all measured neutral-to-worse -- do not revisit
// without a per-dispatch gemm profile.
__global__ __launch_bounds__(256, 2) void gemm_kernel(
        const float* __restrict__ X, const f16* __restrict__ Wf,
        const float* __restrict__ bias, f16* __restrict__ Xp) {
    const int lane = threadIdx.x & 63, wave = threadIdx.x >> 6;
    const int wm = wave >> 1, wn = wave & 1;
    const int q = lane >> 4, rl = lane & 15;
    const int m0 = blockIdx.y * 128 + wm * 64;
    const int n0 = blockIdx.x * 128 + wn * 64;

    const float* aBase[4];
    const f16*   bBase[4];
#pragma unroll
    for (int i = 0; i < 4; i++) {
        aBase[i] = X  + (size_t)(m0 + i * 16 + rl) * 512 + q * 8;
        bBase[i] = Wf + (size_t)(n0 + i * 16 + rl) * 512 + q * 8;
    }

    float4 aR[4][2]; f16x8 bR[4];
#pragma unroll
    for (int i = 0; i < 4; i++) {
        aR[i][0] = *(const float4*)(aBase[i]);
        aR[i][1] = *(const float4*)(aBase[i] + 4);
        bR[i]    = *(const f16x8*)(bBase[i]);
    }

    f32x4 acc[4][4] = {};
    for (int k0 = 0; k0 < 512; k0 += 32) {
        const int kn = (k0 + 32 < 512) ? k0 + 32 : k0;
        float4 aN[4][2]; f16x8 bN[4];
#pragma unroll
        for (int i = 0; i < 4; i++) {           // prefetch next tile
            aN[i][0] = *(const float4*)(aBase[i] + kn);
            aN[i][1] = *(const float4*)(aBase[i] + kn + 4);
            bN[i]    = *(const f16x8*)(bBase[i] + kn);
        }
        f16x8 af[4];
#pragma unroll
        for (int i = 0; i < 4; i++) {           // convert current A tile
            f16x2 p0 = pk(aR[i][0].x, aR[i][0].y);
            f16x2 p1 = pk(aR[i][0].z, aR[i][0].w);
            f16x2 p2 = pk(aR[i][1].x, aR[i][1].y);
            f16x2 p3 = pk(aR[i][1].z, aR[i][1].w);
            f16x8 tv;
            tv[0] = p0[0]; tv[1] = p0[1]; tv[2] = p1[0]; tv[3] = p1[1];
            tv[4] = p2[0]; tv[5] = p2[1]; tv[6] = p3[0]; tv[7] = p3[1];
            af[i] = tv;
        }
#pragma unroll
        for (int i = 0; i < 4; i++)
#pragma unroll
            for (int j = 0; j < 4; j++)
                acc[i][j] = __builtin_amdgcn_mfma_f32_16x16x32_f16(af[i], bR[j], acc[i][j], 0, 0, 0);
#pragma unroll
        for (int i = 0; i < 4; i++) { aR[i][0] = aN[i][0]; aR[i][1] = aN[i][1]; bR[i] = bN[i]; }
    }
#pragma unroll
    for (int j = 0; j < 4; j++) {
        const int n = n0 + j * 16 + rl;
        const float bn = bias[n];
#pragma unroll
        for (int i = 0; i < 4; i++)
#pragma unroll
            for (int r = 0; r < 4; r++) {
                const int m = m0 + i * 16 + q * 4 + r;
                Xp[(size_t)m * 512 + n] = (f16)(-LOG2E * (acc[i][j][r] + bn));
            }
    }
}

// ----------------------------------------------------------------- recurrence (i8 MFMA)
// EXACT R1 structure (449-451us, verified in three independent benches R1/R5/R6).
// 8 WGs x 16 batches; 16 waves (1024 thr), wave w owns row-tiles {2w, 2w+1}.
// ks-outer loop: ds_read bfr[ks] then 2 MFMAs -- LDS reads spread through the MFMA
// stream; 4 waves/SIMD hides epilogue/ds latency. Floors per CU/step: LDS 1540cy
// (16 waves x 8KB @ 85B/cy, the dominant pipe), MFMA 1306cy, VALU ~1000cy; measured
// 2104cy. Falsified alternatives: R2 phase-split (2x reads, 512us), R3 chain-split
// (463us), R4 8-wave (608us), R7/R8 fusion (1165-1260us). Do not revisit.
__global__ __launch_bounds__(1024) void rnn_kernel(
        const char* __restrict__ Whq, const float* __restrict__ scales,
        const f16* __restrict__ Xp, float* __restrict__ out) {
    const int wg = blockIdx.x;          // 0..7
    const int tid = threadIdx.x;
    const int l = tid & 63, w = tid >> 6;   // w in 0..15
    const int bl = l & 15;              // batch lane (N / C col)
    const int q = l >> 4;               // k-quad / C row quad
    const int b = wg * 16 + bl;

    __shared__ __align__(16) uint32_t hT[2][2048];   // 8 KB per buffer, frag-ordered

    // register-resident i8 A-fragments: af[mt][ks], 4 dwords each = 64 regs
    i32x4 af[2][8];
    {
        const i32x4* wp = (const i32x4*)Whq;
#pragma unroll
        for (int mt = 0; mt < 2; mt++)
#pragma unroll
            for (int ks = 0; ks < 8; ks++)
                af[mt][ks] = wp[((w * 2 + mt) * 8 + ks) * 64 + l];
    }
    // per-lane output-row scales (pre-folded with -log2e/127^2)
    float sc[2][4];
#pragma unroll
    for (int mt = 0; mt < 2; mt++)
#pragma unroll
        for (int r = 0; r < 4; r++)
            sc[mt][r] = scales[w * 32 + mt * 16 + q * 4 + r];

    for (int i = tid; i < 2048; i += 1024) hT[0][i] = 0u;
    __syncthreads();

    const f16* xpb = Xp + (size_t)b * 512 + w * 32 + q * 4;
    f16x4 xn0 = *(const f16x4*)(xpb);
    f16x4 xn1 = *(const f16x4*)(xpb + 16);

    const float K127 = 1.0f / 127.0f;
    for (int t = 0; t < T_STEPS; t++) {
        f16x4 xc0 = xn0, xc1 = xn1;
        const size_t tn = (size_t)(t < T_STEPS - 1 ? t + 1 : t) * (BATCH * 512);
        xn0 = *(const f16x4*)(xpb + tn);
        xn1 = *(const f16x4*)(xpb + tn + 16);

        const int rb = t & 1;
        i32x4 acc[2] = {};
        const uint32_t* hrow = &hT[rb][l * 4];
#pragma unroll
        for (int ks = 0; ks < 8; ks++) {
            i32x4 bfr = *(const i32x4*)(hrow + ks * 256);
            acc[0] = __builtin_amdgcn_mfma_i32_16x16x64_i8(af[0][ks], bfr, acc[0], 0, 0, 0);
            acc[1] = __builtin_amdgcn_mfma_i32_16x16x64_i8(af[1][ks], bfr, acc[1], 0, 0, 0);
        }
#pragma unroll
        for (int mt = 0; mt < 2; mt++) {
            uint32_t pkq = 0;
#pragma unroll
            for (int r = 0; r < 4; r++) {
                float tt = fmaf((float)acc[mt][r], sc[mt][r], (float)(mt == 0 ? xc0[r] : xc1[r]));
                float e  = fast_exp2(tt);                // e^{-v}
                float eq = fmaf(e, K127, K127);          // (1+e^{-v})/127
                float sg = fast_rcp(eq) + 0.5f;          // 127*sigmoid + 0.5
                pkq = pack_u8(sg, r, pkq);
            }
            hT[1 - rb][(w * 2 + mt) * 64 + bl * 4 + q] = pkq;
        }
        __syncthreads();
    }
    // final h: read back this lane's own dwords, dequantize i8/127 -> f32
#pragma unroll
    for (int mt = 0; mt < 2; mt++) {
        uint32_t pkq = hT[T_STEPS & 1][(w * 2 + mt) * 64 + bl * 4 + q];
        float4 o;
        o.x = (float)((pkq      ) & 0xFF) * K127;
        o.y = (float)((pkq >>  8) & 0xFF) * K127;
        o.z = (float)((pkq >> 16) & 0xFF) * K127;
        o.w = (float)((pkq >> 24) & 0xFF) * K127;
        *(float4*)(out + (size_t)b * 512 + w * 32 + mt * 16 + q * 4) = o;
    }
}

extern "C" void kernel_launch(void* const* d_in, const int* in_sizes, int n_in,
                              void* d_out, int out_size, void* d_ws, size_t ws_size,
                              hipStream_t stream) {
    const float* X   = (const float*)d_in[0];
    const float* Win = (const float*)d_in[1];
    const float* Wh  = (const float*)d_in[2];
    const float* bh  = (const float*)d_in[3];
    float* out = (float*)d_out;
    char* ws = (char*)d_ws;
    f16* Xp      = (f16*)(ws + XP_OFF);
    f16* Wf      = (f16*)(ws + WF_OFF);
    char* Whq    = (char*)(ws + WHQ_OFF);
    float* Sc    = (float*)(ws + SC_OFF);

    prep_kernel<<<1024, 256, 0, stream>>>(Win, Wf);
    quant_kernel<<<512, 64, 0, stream>>>(Wh, Whq, Sc);
    gemm_kernel<<<dim3(4, 512), 256, 0, stream>>>(X, Wf, bh, Xp);
    rnn_kernel<<<8, 1024, 0, stream>>>(Whq, Sc, Xp, out);
}